// Round 2
// baseline (519.478 us; speedup 1.0000x reference)
//
#include <hip/hip_runtime.h>
#include <hip/hip_bf16.h>

// Head: fused causal attention head. B=4096, T=33, C=512, DK=64.
// q=x@Wq^T, k=x@Wk^T, v=x@Wv^T, S = q k^T * C^-0.5, causal softmax, out = P v.
// Inputs/outputs are FP32 (threshold = 2% of max|ref| -> bf16 internal math OK).

typedef __attribute__((ext_vector_type(8))) short bf16x8;
typedef __attribute__((ext_vector_type(4))) float floatx4;

#define NB 4096
#define TT 33
#define CC 512
#define DKK 64

// LDS strides (bf16 elements unless noted); row strides in dwords are odd
// multiples -> worst 2-way bank aliasing (free, m136).
#define XS 520   // x rows: 33  (512+8)
#define QS 72    // q/k rows: 33 (64+8)
#define VTS 72   // vT rows: 64 (d), cols t 0..63 (zero past 32)
#define SS 52    // S (fp32) rows: 33, cols 0..47
#define PS 72    // P rows: 33, cols 0..63

__device__ __forceinline__ ushort f2b(float f) {
    union { __hip_bfloat16 h; ushort u; } cv;
    cv.h = __float2bfloat16(f);   // RNE
    return cv.u;
}
__device__ __forceinline__ int imin(int a, int b) { return a < b ? a : b; }

__device__ __forceinline__ bf16x8 load8_b(const ushort* p) {
    return *(const bf16x8*)p;
}
__device__ __forceinline__ bf16x8 load8_f(const float* p) {
    float4 f0 = *(const float4*)p;
    float4 f1 = *(const float4*)(p + 4);
    bf16x8 r;
    r[0] = (short)f2b(f0.x); r[1] = (short)f2b(f0.y);
    r[2] = (short)f2b(f0.z); r[3] = (short)f2b(f0.w);
    r[4] = (short)f2b(f1.x); r[5] = (short)f2b(f1.y);
    r[6] = (short)f2b(f1.z); r[7] = (short)f2b(f1.w);
    return r;
}

// Prep: convert W (3 x [64,512] fp32) -> bf16 into ws. grid (32,3) x 256.
__global__ void conv_w_kernel(const float* __restrict__ Wq,
                              const float* __restrict__ Wk,
                              const float* __restrict__ Wv,
                              ushort* __restrict__ wb) {
    const float* src = (blockIdx.y == 0) ? Wq : (blockIdx.y == 1) ? Wk : Wv;
    int i = (blockIdx.x * 256 + threadIdx.x) * 4;   // 0..32764 step 4
    float4 f = *(const float4*)&src[i];
    ushort4 u;
    u.x = f2b(f.x); u.y = f2b(f.y); u.z = f2b(f.z); u.w = f2b(f.w);
    *(ushort4*)&wb[(size_t)blockIdx.y * 32768 + i] = u;
}

template <bool USE_WS>
__global__ __launch_bounds__(256, 2) void head_kernel(
    const float* __restrict__ x,
    const ushort* __restrict__ wb,     // bf16 W (if USE_WS)
    const float* __restrict__ Wqf,
    const float* __restrict__ Wkf,
    const float* __restrict__ Wvf,
    float* __restrict__ out)
{
    __shared__ __align__(16) ushort x_s[TT * XS];
    __shared__ __align__(16) ushort q_s[TT * QS];
    __shared__ __align__(16) ushort k_s[TT * QS];
    __shared__ __align__(16) ushort vT_s[64 * VTS];
    __shared__ __align__(16) float  S_s[TT * SS];
    __shared__ __align__(16) ushort p_s[TT * PS];

    const int b    = blockIdx.x;
    const int tid  = threadIdx.x;
    const int lane = tid & 63;
    const int wave = tid >> 6;
    const int l15  = lane & 15;
    const int quad = lane >> 4;

    // Zero vT so K-padding (t=33..63) contributes exact zeros in PV.
    const uint4 z4 = make_uint4(0u, 0u, 0u, 0u);
    for (int i = tid; i < (64 * VTS) / 8; i += 256)
        ((uint4*)vT_s)[i] = z4;

    // Stage x[b]: 33 rows x 512 fp32 -> bf16 LDS.
    const float* xg = x + (size_t)b * (TT * CC);
    for (int i = tid; i < TT * 128; i += 256) {
        int r = i >> 7, c = (i & 127) << 2;
        float4 f = *(const float4*)&xg[r * CC + c];
        ushort4 u;
        u.x = f2b(f.x); u.y = f2b(f.y); u.z = f2b(f.z); u.w = f2b(f.w);
        *(ushort4*)&x_s[r * XS + c] = u;
    }
    __syncthreads();

    // ---- QKV: [48(pad of 33) x 512] @ [512 x 192] ----
    // Each wave owns 3 of the 12 N-tiles; each W element read once per block.
    {
        floatx4 acc[3][3] = {};   // [m][nl]
        const ushort* wrow_b[3];
        const float*  wrow_f[3];
        int nidx[3];
        #pragma unroll
        for (int nl = 0; nl < 3; nl++) {
            int n = wave * 3 + nl;
            nidx[nl] = n;
            int mat = n >> 2;
            int row = (n & 3) * 16 + l15;
            if (USE_WS) {
                wrow_b[nl] = wb + (size_t)mat * 32768 + (size_t)row * CC;
                wrow_f[nl] = nullptr;
            } else {
                const float* Wf = (mat == 0) ? Wqf : (mat == 1) ? Wkf : Wvf;
                wrow_f[nl] = Wf + (size_t)row * CC;
                wrow_b[nl] = nullptr;
            }
        }
        const int r0 = l15, r1 = 16 + l15, r2 = 32;  // m=2 clamped to row 32
        for (int ks = 0; ks < 16; ks++) {
            int c = ks * 32 + quad * 8;
            bf16x8 a0 = *(const bf16x8*)&x_s[r0 * XS + c];
            bf16x8 a1 = *(const bf16x8*)&x_s[r1 * XS + c];
            bf16x8 a2 = *(const bf16x8*)&x_s[r2 * XS + c];
            bf16x8 b0 = USE_WS ? load8_b(&wrow_b[0][c]) : load8_f(&wrow_f[0][c]);
            bf16x8 b1 = USE_WS ? load8_b(&wrow_b[1][c]) : load8_f(&wrow_f[1][c]);
            bf16x8 b2 = USE_WS ? load8_b(&wrow_b[2][c]) : load8_f(&wrow_f[2][c]);
            acc[0][0] = __builtin_amdgcn_mfma_f32_16x16x32_bf16(a0, b0, acc[0][0], 0, 0, 0);
            acc[1][0] = __builtin_amdgcn_mfma_f32_16x16x32_bf16(a1, b0, acc[1][0], 0, 0, 0);
            acc[2][0] = __builtin_amdgcn_mfma_f32_16x16x32_bf16(a2, b0, acc[2][0], 0, 0, 0);
            acc[0][1] = __builtin_amdgcn_mfma_f32_16x16x32_bf16(a0, b1, acc[0][1], 0, 0, 0);
            acc[1][1] = __builtin_amdgcn_mfma_f32_16x16x32_bf16(a1, b1, acc[1][1], 0, 0, 0);
            acc[2][1] = __builtin_amdgcn_mfma_f32_16x16x32_bf16(a2, b1, acc[2][1], 0, 0, 0);
            acc[0][2] = __builtin_amdgcn_mfma_f32_16x16x32_bf16(a0, b2, acc[0][2], 0, 0, 0);
            acc[1][2] = __builtin_amdgcn_mfma_f32_16x16x32_bf16(a1, b2, acc[1][2], 0, 0, 0);
            acc[2][2] = __builtin_amdgcn_mfma_f32_16x16x32_bf16(a2, b2, acc[2][2], 0, 0, 0);
        }
        // Scatter: q/k row-major, v transposed (vT[d][t]).
        #pragma unroll
        for (int nl = 0; nl < 3; nl++) {
            int n = nidx[nl];
            int mat = n >> 2;
            int col = (n & 3) * 16 + l15;
            #pragma unroll
            for (int m = 0; m < 3; m++) {
                #pragma unroll
                for (int r = 0; r < 4; r++) {
                    int row = m * 16 + quad * 4 + r;   // t, C/D layout (m89)
                    if (row < TT) {
                        ushort v = f2b(acc[m][nl][r]);
                        if (mat == 0)      q_s[row * QS + col] = v;
                        else if (mat == 1) k_s[row * QS + col] = v;
                        else               vT_s[col * VTS + row] = v;
                    }
                }
            }
        }
    }
    __syncthreads();

    // ---- S = q k^T * scale : 9 tiles of 16x16, K=64 ----
    const float scale = 0.044194173824159216f;  // 512^-0.5
    for (int g = wave; g < 9; g += 4) {
        int mt = g / 3, nt = g - mt * 3;
        floatx4 s = {};
        int ra = imin(mt * 16 + l15, 32);
        int rb = imin(nt * 16 + l15, 32);
        #pragma unroll
        for (int ks = 0; ks < 2; ks++) {
            int c = ks * 32 + quad * 8;
            bf16x8 aq = *(const bf16x8*)&q_s[ra * QS + c];
            bf16x8 bk = *(const bf16x8*)&k_s[rb * QS + c];
            s = __builtin_amdgcn_mfma_f32_16x16x32_bf16(aq, bk, s, 0, 0, 0);
        }
        #pragma unroll
        for (int r = 0; r < 4; r++) {
            int row = mt * 16 + quad * 4 + r;
            int col = nt * 16 + l15;
            if (row < TT) S_s[row * SS + col] = s[r] * scale;
        }
    }
    __syncthreads();

    // ---- causal softmax, one thread per row (33 rows) ----
    if (tid < TT) {
        float* Sr = &S_s[tid * SS];
        float mx = -1e30f;
        for (int c = 0; c <= tid; c++) mx = fmaxf(mx, Sr[c]);
        float sum = 0.f;
        for (int c = 0; c <= tid; c++) { float e = __expf(Sr[c] - mx); Sr[c] = e; sum += e; }
        float inv = 1.f / sum;
        ushort* Pr = &p_s[tid * PS];
        int c = 0;
        for (; c <= tid; c++) Pr[c] = f2b(Sr[c] * inv);
        for (; c < 64; c++)  Pr[c] = 0;   // masked + K-padding cols
    }
    __syncthreads();

    // ---- out = P v : 12 tiles of 16x16, K=64 (cols>=33 exact zeros) ----
    float* og = out + (size_t)b * (TT * DKK);
    for (int g = wave; g < 12; g += 4) {
        int mt = g >> 2, nt = g & 3;
        floatx4 o = {};
        int ra = imin(mt * 16 + l15, 32);
        int rb = nt * 16 + l15;              // d row of vT
        #pragma unroll
        for (int ks = 0; ks < 2; ks++) {
            int c = ks * 32 + quad * 8;
            bf16x8 ap = *(const bf16x8*)&p_s[ra * PS + c];
            bf16x8 bv = *(const bf16x8*)&vT_s[rb * VTS + c];
            o = __builtin_amdgcn_mfma_f32_16x16x32_bf16(ap, bv, o, 0, 0, 0);
        }
        #pragma unroll
        for (int r = 0; r < 4; r++) {
            int t = mt * 16 + quad * 4 + r;
            if (t < TT) og[t * DKK + nt * 16 + l15] = o[r];
        }
    }
}

extern "C" void kernel_launch(void* const* d_in, const int* in_sizes, int n_in,
                              void* d_out, int out_size, void* d_ws, size_t ws_size,
                              hipStream_t stream) {
    const float* x  = (const float*)d_in[0];
    const float* Wq = (const float*)d_in[1];
    const float* Wk = (const float*)d_in[2];
    const float* Wv = (const float*)d_in[3];
    float* out = (float*)d_out;

    if (ws_size >= 3u * 64u * 512u * sizeof(ushort)) {
        ushort* wb = (ushort*)d_ws;
        conv_w_kernel<<<dim3(32, 3), 256, 0, stream>>>(Wq, Wk, Wv, wb);
        head_kernel<true><<<NB, 256, 0, stream>>>(x, wb, Wq, Wk, Wv, out);
    } else {
        head_kernel<false><<<NB, 256, 0, stream>>>(x, nullptr, Wq, Wk, Wv, out);
    }
}

// Round 3
// 463.304 us; speedup vs baseline: 1.1212x; 1.1212x over previous
//
#include <hip/hip_runtime.h>
#include <hip/hip_bf16.h>

// Head: fused causal attention head. B=4096, T=33, C=512, DK=64.
// q=x@Wq^T, k=x@Wk^T, v=x@Wv^T, S = q k^T * C^-0.5, causal softmax, out = P v.
// fp32 in/out; bf16 internal (threshold = 2% of max|ref|).
//
// R3: LDS overlay (x_s reused for q/k/vT/P/S after QKV) -> 34.3KB, 4 blocks/CU;
//     register-vectorized softmax (no dependent LDS-read chain).

typedef __attribute__((ext_vector_type(8))) short bf16x8;
typedef __attribute__((ext_vector_type(4))) float floatx4;

#define NB 4096
#define TT 33
#define CC 512

#define XS   520   // x_s stride (ushort), 33 rows
#define QS   72    // q/k/vT/p stride (ushort)
#define SSTR 36    // S stride (float)

// byte offsets of the post-QKV overlay inside smem (all 16B aligned)
#define OFF_Q   0
#define OFF_K   4752
#define OFF_VT  9504      // 64 x 72 ushort = 9216
#define OFF_P   18720
#define OFF_S   23472     // 33 x 36 float = 4752 -> end 28224
#define SMEM_BYTES 34320  // 33 x 520 x 2 (x_s dominates)

__device__ __forceinline__ ushort f2b(float f) {
    union { __hip_bfloat16 h; ushort u; } cv;
    cv.h = __float2bfloat16(f);   // RNE
    return cv.u;
}
__device__ __forceinline__ int imin(int a, int b) { return a < b ? a : b; }

__device__ __forceinline__ bf16x8 load8_b(const ushort* p) { return *(const bf16x8*)p; }
__device__ __forceinline__ bf16x8 load8_f(const float* p) {
    float4 f0 = *(const float4*)p;
    float4 f1 = *(const float4*)(p + 4);
    bf16x8 r;
    r[0] = (short)f2b(f0.x); r[1] = (short)f2b(f0.y);
    r[2] = (short)f2b(f0.z); r[3] = (short)f2b(f0.w);
    r[4] = (short)f2b(f1.x); r[5] = (short)f2b(f1.y);
    r[6] = (short)f2b(f1.z); r[7] = (short)f2b(f1.w);
    return r;
}

// Prep: W (3 x [64,512] fp32) -> bf16 in ws. grid (32,3) x 256.
__global__ void conv_w_kernel(const float* __restrict__ Wq,
                              const float* __restrict__ Wk,
                              const float* __restrict__ Wv,
                              ushort* __restrict__ wb) {
    const float* src = (blockIdx.y == 0) ? Wq : (blockIdx.y == 1) ? Wk : Wv;
    int i = (blockIdx.x * 256 + threadIdx.x) * 4;
    float4 f = *(const float4*)&src[i];
    ushort4 u;
    u.x = f2b(f.x); u.y = f2b(f.y); u.z = f2b(f.z); u.w = f2b(f.w);
    *(ushort4*)&wb[(size_t)blockIdx.y * 32768 + i] = u;
}

template <bool USE_WS>
__global__ __launch_bounds__(256, 4) void head_kernel(
    const float* __restrict__ x,
    const ushort* __restrict__ wb,
    const float* __restrict__ Wqf,
    const float* __restrict__ Wkf,
    const float* __restrict__ Wvf,
    float* __restrict__ out)
{
    __shared__ __align__(16) char smem[SMEM_BYTES];
    ushort* x_s  = (ushort*)smem;
    ushort* q_s  = (ushort*)(smem + OFF_Q);
    ushort* k_s  = (ushort*)(smem + OFF_K);
    ushort* vT_s = (ushort*)(smem + OFF_VT);
    ushort* p_s  = (ushort*)(smem + OFF_P);
    float*  S_s  = (float*)(smem + OFF_S);

    const int b    = blockIdx.x;
    const int tid  = threadIdx.x;
    const int lane = tid & 63;
    const int wave = tid >> 6;
    const int l15  = lane & 15;
    const int quad = lane >> 4;

    // ---- Phase 0: stage x[b] fp32 -> bf16 LDS ----
    const float* xg = x + (size_t)b * (TT * CC);
    for (int i = tid; i < TT * 128; i += 256) {
        int r = i >> 7, c = (i & 127) << 2;
        float4 f = *(const float4*)&xg[r * CC + c];
        ushort4 u;
        u.x = f2b(f.x); u.y = f2b(f.y); u.z = f2b(f.z); u.w = f2b(f.w);
        *(ushort4*)&x_s[r * XS + c] = u;
    }
    __syncthreads();

    // ---- Phase 1: QKV MFMA (acc stays in registers) ----
    floatx4 acc[3][3] = {};   // [m][nl]
    int nidx[3];
    const ushort* wrow_b[3];
    const float*  wrow_f[3];
    #pragma unroll
    for (int nl = 0; nl < 3; nl++) {
        int n = wave * 3 + nl;
        nidx[nl] = n;
        int mat = n >> 2;
        int row = (n & 3) * 16 + l15;
        if (USE_WS) {
            wrow_b[nl] = wb + (size_t)mat * 32768 + (size_t)row * CC;
            wrow_f[nl] = nullptr;
        } else {
            const float* Wf = (mat == 0) ? Wqf : (mat == 1) ? Wkf : Wvf;
            wrow_f[nl] = Wf + (size_t)row * CC;
            wrow_b[nl] = nullptr;
        }
    }
    {
        const int r0 = l15, r1 = 16 + l15, r2 = 32;  // m=2 tile clamped to row 32
        for (int ks = 0; ks < 16; ks++) {
            int c = ks * 32 + quad * 8;
            bf16x8 a0 = *(const bf16x8*)&x_s[r0 * XS + c];
            bf16x8 a1 = *(const bf16x8*)&x_s[r1 * XS + c];
            bf16x8 a2 = *(const bf16x8*)&x_s[r2 * XS + c];
            bf16x8 b0 = USE_WS ? load8_b(&wrow_b[0][c]) : load8_f(&wrow_f[0][c]);
            bf16x8 b1 = USE_WS ? load8_b(&wrow_b[1][c]) : load8_f(&wrow_f[1][c]);
            bf16x8 b2 = USE_WS ? load8_b(&wrow_b[2][c]) : load8_f(&wrow_f[2][c]);
            acc[0][0] = __builtin_amdgcn_mfma_f32_16x16x32_bf16(a0, b0, acc[0][0], 0, 0, 0);
            acc[1][0] = __builtin_amdgcn_mfma_f32_16x16x32_bf16(a1, b0, acc[1][0], 0, 0, 0);
            acc[2][0] = __builtin_amdgcn_mfma_f32_16x16x32_bf16(a2, b0, acc[2][0], 0, 0, 0);
            acc[0][1] = __builtin_amdgcn_mfma_f32_16x16x32_bf16(a0, b1, acc[0][1], 0, 0, 0);
            acc[1][1] = __builtin_amdgcn_mfma_f32_16x16x32_bf16(a1, b1, acc[1][1], 0, 0, 0);
            acc[2][1] = __builtin_amdgcn_mfma_f32_16x16x32_bf16(a2, b1, acc[2][1], 0, 0, 0);
            acc[0][2] = __builtin_amdgcn_mfma_f32_16x16x32_bf16(a0, b2, acc[0][2], 0, 0, 0);
            acc[1][2] = __builtin_amdgcn_mfma_f32_16x16x32_bf16(a1, b2, acc[1][2], 0, 0, 0);
            acc[2][2] = __builtin_amdgcn_mfma_f32_16x16x32_bf16(a2, b2, acc[2][2], 0, 0, 0);
        }
    }
    // x_s dead for all waves only after this barrier; overlay writes follow.
    __syncthreads();

    // ---- Phase 2: zero vT strip t in [33,64), then scatter q/k/vT ----
    for (int i = tid; i < 64 * 32; i += 256) {
        int d = i >> 5, t = i & 31;
        if (t) vT_s[d * QS + 32 + t] = 0;   // t=33..63 only (t=32 is scattered below)
    }
    #pragma unroll
    for (int nl = 0; nl < 3; nl++) {
        int n = nidx[nl];
        int mat = n >> 2;                  // 0=q 1=k 2=v
        int col = (n & 3) * 16 + l15;
        #pragma unroll
        for (int m = 0; m < 3; m++) {
            #pragma unroll
            for (int r = 0; r < 4; r++) {
                int row = m * 16 + quad * 4 + r;   // t  (C/D layout, m89)
                if (row < TT) {
                    ushort v = f2b(acc[m][nl][r]);
                    if (mat == 0)      q_s[row * QS + col] = v;
                    else if (mat == 1) k_s[row * QS + col] = v;
                    else               vT_s[col * QS + row] = v;
                }
            }
        }
    }
    __syncthreads();

    // ---- Phase 3: S = q k^T * scale (9 tiles 16x16, K=64) ----
    const float scale = 0.044194173824159216f;  // 512^-0.5
    for (int g = wave; g < 9; g += 4) {
        int mt = g / 3, nt = g - mt * 3;
        floatx4 s = {};
        int ra = imin(mt * 16 + l15, 32);
        int rb = imin(nt * 16 + l15, 32);
        #pragma unroll
        for (int ks = 0; ks < 2; ks++) {
            int c = ks * 32 + quad * 8;
            bf16x8 aq = *(const bf16x8*)&q_s[ra * QS + c];
            bf16x8 bk = *(const bf16x8*)&k_s[rb * QS + c];
            s = __builtin_amdgcn_mfma_f32_16x16x32_bf16(aq, bk, s, 0, 0, 0);
        }
        #pragma unroll
        for (int r = 0; r < 4; r++) {
            int row = mt * 16 + quad * 4 + r;
            int col = nt * 16 + l15;
            if (row < TT && col < TT) S_s[row * SSTR + col] = s[r] * scale;
        }
    }
    __syncthreads();

    // ---- Phase 4: causal softmax, one thread per row, register-vectorized ----
    if (tid < TT) {
        const float* Sr = &S_s[tid * SSTR];
        float4 f[9];                       // cols 0..35 (33..35 garbage, masked)
        #pragma unroll
        for (int j = 0; j < 9; j++) f[j] = *(const float4*)&Sr[4 * j];
        const float* fv = (const float*)f;
        float mx = -1e30f;
        #pragma unroll
        for (int c = 0; c < TT; c++)
            mx = fmaxf(mx, (c <= tid) ? fv[c] : -1e30f);
        float e[TT];
        float sum = 0.f;
        #pragma unroll
        for (int c = 0; c < TT; c++) {
            float t = __expf(fv[c] - mx);
            e[c] = (c <= tid) ? t : 0.f;
            sum += e[c];
        }
        float inv = 1.f / sum;
        ushort* Pr = &p_s[tid * QS];
        #pragma unroll
        for (int j = 0; j < 16; j++) {     // cols 0..31 packed pairs
            uint pk = (uint)f2b(e[2 * j] * inv) | ((uint)f2b(e[2 * j + 1] * inv) << 16);
            *(uint*)&Pr[2 * j] = pk;
        }
        Pr[32] = f2b(e[32] * inv);
        Pr[33] = 0;
        #pragma unroll
        for (int j = 0; j < 15; j++)       // cols 34..63 zero pairs
            *(uint*)&Pr[34 + 2 * j] = 0u;
    }
    __syncthreads();

    // ---- Phase 5: out = P v (12 tiles 16x16, K=64; cols>=33 exact zeros) ----
    float* og = out + (size_t)b * (TT * 64);
    for (int g = wave; g < 12; g += 4) {
        int mt = g >> 2, nt = g & 3;
        floatx4 o = {};
        int ra = imin(mt * 16 + l15, 32);
        int rb = nt * 16 + l15;            // d row of vT
        #pragma unroll
        for (int ks = 0; ks < 2; ks++) {
            int c = ks * 32 + quad * 8;
            bf16x8 ap = *(const bf16x8*)&p_s[ra * QS + c];
            bf16x8 bv = *(const bf16x8*)&vT_s[rb * QS + c];
            o = __builtin_amdgcn_mfma_f32_16x16x32_bf16(ap, bv, o, 0, 0, 0);
        }
        #pragma unroll
        for (int r = 0; r < 4; r++) {
            int t = mt * 16 + quad * 4 + r;
            if (t < TT) og[t * 64 + nt * 16 + l15] = o[r];
        }
    }
}

extern "C" void kernel_launch(void* const* d_in, const int* in_sizes, int n_in,
                              void* d_out, int out_size, void* d_ws, size_t ws_size,
                              hipStream_t stream) {
    const float* x  = (const float*)d_in[0];
    const float* Wq = (const float*)d_in[1];
    const float* Wk = (const float*)d_in[2];
    const float* Wv = (const float*)d_in[3];
    float* out = (float*)d_out;

    if (ws_size >= 3u * 64u * 512u * sizeof(ushort)) {
        ushort* wb = (ushort*)d_ws;
        conv_w_kernel<<<dim3(32, 3), 256, 0, stream>>>(Wq, Wk, Wv, wb);
        head_kernel<true><<<NB, 256, 0, stream>>>(x, wb, nullptr, nullptr, nullptr, out);
    } else {
        head_kernel<false><<<NB, 256, 0, stream>>>(x, nullptr, Wq, Wk, Wv, out);
    }
}

// Round 4
// 451.980 us; speedup vs baseline: 1.1493x; 1.0251x over previous
//
#include <hip/hip_runtime.h>
#include <hip/hip_bf16.h>

// Head: fused causal attention head. B=4096, T=33, C=512, DK=64.
// q=x@Wq^T, k=x@Wk^T, v=x@Wv^T, S = q k^T * C^-0.5, causal softmax, out = P v.
// fp32 in/out; bf16 internal (threshold = 2% of max|ref|).
//
// R4: (1) batched staging loads (17 dwordx4 in flight/thread -> HBM saturation;
//     R3's VGPR=52 allowed only ~5 -> 918 GB/s). (2) per-wave attention tail:
//     full S per wave, shuffle-butterfly softmax, wave-private P strip, PV
//     quarter per wave -> 3 barriers instead of 5, no serial softmax.
//     (3) 1/sum deferred to fp32 epilogue.

typedef __attribute__((ext_vector_type(8))) short bf16x8;
typedef __attribute__((ext_vector_type(4))) float floatx4;

#define NB 4096
#define TT 33
#define CC 512

#define XS 520        // x_s stride (ushort): 33 rows -> 34320 B
#define QS 72         // q/k/vT/P stride (ushort)
// Overlay (aliases x_s; valid after barrier 2):
#define OFF_Q  0
#define OFF_K  4752
#define OFF_VT 9504   // 64*72*2 = 9216 -> end 18720
#define OFF_P  18720  // + wave*4752 -> end 37728
#define SMEM_BYTES 37728

__device__ __forceinline__ ushort f2b(float f) {
    union { __hip_bfloat16 h; ushort u; } cv;
    cv.h = __float2bfloat16(f);   // RNE
    return cv.u;
}
__device__ __forceinline__ int imin(int a, int b) { return a < b ? a : b; }

__device__ __forceinline__ bf16x8 load8_b(const ushort* p) { return *(const bf16x8*)p; }
__device__ __forceinline__ bf16x8 load8_f(const float* p) {
    float4 f0 = *(const float4*)p;
    float4 f1 = *(const float4*)(p + 4);
    bf16x8 r;
    r[0] = (short)f2b(f0.x); r[1] = (short)f2b(f0.y);
    r[2] = (short)f2b(f0.z); r[3] = (short)f2b(f0.w);
    r[4] = (short)f2b(f1.x); r[5] = (short)f2b(f1.y);
    r[6] = (short)f2b(f1.z); r[7] = (short)f2b(f1.w);
    return r;
}

// Prep: W (3 x [64,512] fp32) -> bf16 in ws. grid (32,3) x 256.
__global__ void conv_w_kernel(const float* __restrict__ Wq,
                              const float* __restrict__ Wk,
                              const float* __restrict__ Wv,
                              ushort* __restrict__ wb) {
    const float* src = (blockIdx.y == 0) ? Wq : (blockIdx.y == 1) ? Wk : Wv;
    int i = (blockIdx.x * 256 + threadIdx.x) * 4;
    float4 f = *(const float4*)&src[i];
    ushort4 u;
    u.x = f2b(f.x); u.y = f2b(f.y); u.z = f2b(f.z); u.w = f2b(f.w);
    *(ushort4*)&wb[(size_t)blockIdx.y * 32768 + i] = u;
}

template <bool USE_WS>
__global__ __launch_bounds__(256, 4) void head_kernel(
    const float* __restrict__ x,
    const ushort* __restrict__ wb,
    const float* __restrict__ Wqf,
    const float* __restrict__ Wkf,
    const float* __restrict__ Wvf,
    float* __restrict__ out)
{
    __shared__ __align__(16) char smem[SMEM_BYTES];
    ushort* x_s  = (ushort*)smem;
    ushort* q_s  = (ushort*)(smem + OFF_Q);
    ushort* k_s  = (ushort*)(smem + OFF_K);
    ushort* vT_s = (ushort*)(smem + OFF_VT);

    const int b    = blockIdx.x;
    const int tid  = threadIdx.x;
    const int lane = tid & 63;
    const int wave = tid >> 6;
    const int l15  = lane & 15;
    const int quad = lane >> 4;

    ushort* Pw = (ushort*)(smem + OFF_P) + wave * (TT * QS);  // wave-private

    // ---- Phase 0: stage x[b] fp32 -> bf16 LDS, loads batched for MLP ----
    const float* xg = x + (size_t)b * (TT * CC);
    {
        float4 buf[17];                     // 4224 float4 total, 256 threads
        #pragma unroll
        for (int j = 0; j < 17; j++) {
            int i = tid + j * 256;
            if (i < 4224) buf[j] = ((const float4*)xg)[i];
        }
        #pragma unroll
        for (int j = 0; j < 17; j++) {
            int i = tid + j * 256;
            if (i < 4224) {
                int r = i >> 7, c = (i & 127) << 2;
                ushort4 u;
                u.x = f2b(buf[j].x); u.y = f2b(buf[j].y);
                u.z = f2b(buf[j].z); u.w = f2b(buf[j].w);
                *(ushort4*)&x_s[r * XS + c] = u;
            }
        }
    }
    __syncthreads();   // barrier 1

    // ---- Phase 1: QKV MFMA (acc in registers/AGPRs) ----
    floatx4 acc[3][3] = {};   // [m][nl]
    int nidx[3];
    const ushort* wrow_b[3];
    const float*  wrow_f[3];
    #pragma unroll
    for (int nl = 0; nl < 3; nl++) {
        int n = wave * 3 + nl;
        nidx[nl] = n;
        int mat = n >> 2;
        int row = (n & 3) * 16 + l15;
        if (USE_WS) {
            wrow_b[nl] = wb + (size_t)mat * 32768 + (size_t)row * CC;
            wrow_f[nl] = nullptr;
        } else {
            const float* Wf = (mat == 0) ? Wqf : (mat == 1) ? Wkf : Wvf;
            wrow_f[nl] = Wf + (size_t)row * CC;
            wrow_b[nl] = nullptr;
        }
    }
    {
        const int r0 = l15, r1 = 16 + l15, r2 = 32;  // m=2 tile clamped to 32
        for (int ks = 0; ks < 16; ks++) {
            int c = ks * 32 + quad * 8;
            bf16x8 a0 = *(const bf16x8*)&x_s[r0 * XS + c];
            bf16x8 a1 = *(const bf16x8*)&x_s[r1 * XS + c];
            bf16x8 a2 = *(const bf16x8*)&x_s[r2 * XS + c];
            bf16x8 b0 = USE_WS ? load8_b(&wrow_b[0][c]) : load8_f(&wrow_f[0][c]);
            bf16x8 b1 = USE_WS ? load8_b(&wrow_b[1][c]) : load8_f(&wrow_f[1][c]);
            bf16x8 b2 = USE_WS ? load8_b(&wrow_b[2][c]) : load8_f(&wrow_f[2][c]);
            acc[0][0] = __builtin_amdgcn_mfma_f32_16x16x32_bf16(a0, b0, acc[0][0], 0, 0, 0);
            acc[1][0] = __builtin_amdgcn_mfma_f32_16x16x32_bf16(a1, b0, acc[1][0], 0, 0, 0);
            acc[2][0] = __builtin_amdgcn_mfma_f32_16x16x32_bf16(a2, b0, acc[2][0], 0, 0, 0);
            acc[0][1] = __builtin_amdgcn_mfma_f32_16x16x32_bf16(a0, b1, acc[0][1], 0, 0, 0);
            acc[1][1] = __builtin_amdgcn_mfma_f32_16x16x32_bf16(a1, b1, acc[1][1], 0, 0, 0);
            acc[2][1] = __builtin_amdgcn_mfma_f32_16x16x32_bf16(a2, b1, acc[2][1], 0, 0, 0);
            acc[0][2] = __builtin_amdgcn_mfma_f32_16x16x32_bf16(a0, b2, acc[0][2], 0, 0, 0);
            acc[1][2] = __builtin_amdgcn_mfma_f32_16x16x32_bf16(a1, b2, acc[1][2], 0, 0, 0);
            acc[2][2] = __builtin_amdgcn_mfma_f32_16x16x32_bf16(a2, b2, acc[2][2], 0, 0, 0);
        }
    }
    __syncthreads();   // barrier 2: x_s dead; overlay writes may begin

    // ---- Phase 2: zero vT strip t in [33,64), scatter q/k/vT ----
    for (int i = tid; i < 64 * 32; i += 256) {
        int d = i >> 5, t = i & 31;
        if (t) vT_s[d * QS + 32 + t] = 0;   // t = 33..63
    }
    #pragma unroll
    for (int nl = 0; nl < 3; nl++) {
        int n = nidx[nl];
        int mat = n >> 2;                  // 0=q 1=k 2=v
        int col = (n & 3) * 16 + l15;
        #pragma unroll
        for (int m = 0; m < 3; m++) {
            #pragma unroll
            for (int r = 0; r < 4; r++) {
                int row = m * 16 + quad * 4 + r;   // t (C/D layout, m89)
                if (row < TT) {
                    ushort v = f2b(acc[m][nl][r]);
                    if (mat == 0)      q_s[row * QS + col] = v;
                    else if (mat == 1) k_s[row * QS + col] = v;
                    else               vT_s[col * QS + row] = v;
                }
            }
        }
    }
    __syncthreads();   // barrier 3: q/k/vT complete. Tail is barrier-free.

    // ---- Phase 3 (per wave): full S = q k^T, register softmax ----
    bf16x8 aq[3][2], bk[3][2];
    #pragma unroll
    for (int m = 0; m < 3; m++) {
        int rr = imin(m * 16 + l15, 32);
        aq[m][0] = *(const bf16x8*)&q_s[rr * QS + quad * 8];
        aq[m][1] = *(const bf16x8*)&q_s[rr * QS + 32 + quad * 8];
        bk[m][0] = *(const bf16x8*)&k_s[rr * QS + quad * 8];
        bk[m][1] = *(const bf16x8*)&k_s[rr * QS + 32 + quad * 8];
    }
    floatx4 s[3][3] = {};
    #pragma unroll
    for (int mt = 0; mt < 3; mt++)
        #pragma unroll
        for (int nt = 0; nt < 3; nt++) {
            s[mt][nt] = __builtin_amdgcn_mfma_f32_16x16x32_bf16(aq[mt][0], bk[nt][0], s[mt][nt], 0, 0, 0);
            s[mt][nt] = __builtin_amdgcn_mfma_f32_16x16x32_bf16(aq[mt][1], bk[nt][1], s[mt][nt], 0, 0, 0);
        }

    const float scale = 0.044194173824159216f;  // 512^-0.5
    // mask + scale
    #pragma unroll
    for (int mt = 0; mt < 3; mt++)
        #pragma unroll
        for (int nt = 0; nt < 3; nt++)
            #pragma unroll
            for (int r = 0; r < 4; r++) {
                int row = mt * 16 + quad * 4 + r;
                int col = nt * 16 + l15;
                float v = s[mt][nt][r] * scale;
                s[mt][nt][r] = (col <= row) ? v : -1e30f;
            }
    // row-wise max & sum via 16-lane butterflies (cols live on l15)
    float inv_s[3][4];
    #pragma unroll
    for (int mt = 0; mt < 3; mt++)
        #pragma unroll
        for (int r = 0; r < 4; r++) {
            float m = fmaxf(fmaxf(s[mt][0][r], s[mt][1][r]), s[mt][2][r]);
            #pragma unroll
            for (int d = 1; d < 16; d <<= 1) m = fmaxf(m, __shfl_xor(m, d));
            float sum = 0.f;
            #pragma unroll
            for (int nt = 0; nt < 3; nt++) {
                float e = __expf(s[mt][nt][r] - m);
                s[mt][nt][r] = e;
                sum += e;
            }
            #pragma unroll
            for (int d = 1; d < 16; d <<= 1) sum += __shfl_xor(sum, d);
            inv_s[mt][r] = 1.f / sum;
        }

    // ---- Phase 4 (per wave): P -> private LDS strip (rows 0..32) ----
    // cols 33..47 are exp(-1e30-m)=0 from the scatter; zero-fill cols 48..63.
    for (int i = lane; i < TT * 8; i += 64) {
        int r = i >> 3, c = 48 + ((i & 7) << 1);
        *(uint*)&Pw[r * QS + c] = 0u;
    }
    #pragma unroll
    for (int mt = 0; mt < 3; mt++)
        #pragma unroll
        for (int nt = 0; nt < 3; nt++)
            #pragma unroll
            for (int r = 0; r < 4; r++) {
                int row = mt * 16 + quad * 4 + r;
                if (row < TT) Pw[row * QS + nt * 16 + l15] = f2b(s[mt][nt][r]);
            }

    // ---- Phase 5 (per wave): out quarter nt=wave: O = P v, * inv in epilogue ----
    const int dcol = wave * 16 + l15;
    bf16x8 bv0 = *(const bf16x8*)&vT_s[dcol * QS + quad * 8];
    bf16x8 bv1 = *(const bf16x8*)&vT_s[dcol * QS + 32 + quad * 8];
    float* og = out + (size_t)b * (TT * 64);
    #pragma unroll
    for (int mt = 0; mt < 3; mt++) {
        int ra = imin(mt * 16 + l15, 32);
        bf16x8 ap0 = *(const bf16x8*)&Pw[ra * QS + quad * 8];
        bf16x8 ap1 = *(const bf16x8*)&Pw[ra * QS + 32 + quad * 8];
        floatx4 o = {};
        o = __builtin_amdgcn_mfma_f32_16x16x32_bf16(ap0, bv0, o, 0, 0, 0);
        o = __builtin_amdgcn_mfma_f32_16x16x32_bf16(ap1, bv1, o, 0, 0, 0);
        #pragma unroll
        for (int r = 0; r < 4; r++) {
            int row = mt * 16 + quad * 4 + r;
            if (row < TT) og[row * 64 + dcol] = o[r] * inv_s[mt][r];
        }
    }
}

extern "C" void kernel_launch(void* const* d_in, const int* in_sizes, int n_in,
                              void* d_out, int out_size, void* d_ws, size_t ws_size,
                              hipStream_t stream) {
    const float* x  = (const float*)d_in[0];
    const float* Wq = (const float*)d_in[1];
    const float* Wk = (const float*)d_in[2];
    const float* Wv = (const float*)d_in[3];
    float* out = (float*)d_out;

    if (ws_size >= 3u * 64u * 512u * sizeof(ushort)) {
        ushort* wb = (ushort*)d_ws;
        conv_w_kernel<<<dim3(32, 3), 256, 0, stream>>>(Wq, Wk, Wv, wb);
        head_kernel<true><<<NB, 256, 0, stream>>>(x, wb, nullptr, nullptr, nullptr, out);
    } else {
        head_kernel<false><<<NB, 256, 0, stream>>>(x, nullptr, Wq, Wk, Wv, out);
    }
}